// Round 11
// baseline (257.920 us; speedup 1.0000x reference)
//
#include <hip/hip_runtime.h>
#include <type_traits>

typedef short bf16x8 __attribute__((ext_vector_type(8)));
typedef float f32x4  __attribute__((ext_vector_type(4)));
typedef unsigned short u16;

#define MFMA(a,b,c) __builtin_amdgcn_mfma_f32_16x16x32_bf16((a),(b),(c),0,0,0)

__device__ __forceinline__ float bf2f(u16 u){ unsigned x=((unsigned)u)<<16; return __builtin_bit_cast(float,x); }
__device__ __forceinline__ u16 f2bf(float f){ unsigned x=__builtin_bit_cast(unsigned,f); x += 0x7fffu + ((x>>16)&1u); return (u16)(x>>16); }

#if __has_builtin(__builtin_amdgcn_cvt_pk_bf16_f32)
typedef __bf16 hwbf2 __attribute__((ext_vector_type(2)));
__device__ __forceinline__ unsigned pkbf(float a, float b){
  hwbf2 r = __builtin_amdgcn_cvt_pk_bf16_f32(a, b);   // lo=a, hi=b, RNE
  return __builtin_bit_cast(unsigned, r);
}
#else
__device__ __forceinline__ unsigned pkbf(float a, float b){
  unsigned ua = __builtin_bit_cast(unsigned, a), ub = __builtin_bit_cast(unsigned, b);
  ua += 0x7fffu + ((ua>>16)&1u);
  ub += 0x7fffu + ((ub>>16)&1u);
  return __builtin_amdgcn_perm(ub, ua, 0x07060302u);
}
#endif

#if __has_builtin(__builtin_amdgcn_exp2f)
#define EXP2(x) __builtin_amdgcn_exp2f(x)
#else
#define EXP2(x) exp2f(x)
#endif

__device__ __forceinline__ void async_cp16(const u16* g, u16* l){
  __builtin_amdgcn_global_load_lds((const __attribute__((address_space(1))) void*)g,
                                   (__attribute__((address_space(3))) void*)l, 16, 0, 0);
}

// ---------------- fused prep: cvt H->bf16, transpose Wqkv & Wproj to bf16 ----------------
// flat grid 8192: [0,4096) cvt; [4096,7168) Wqkv^T; [7168,8192) Wproj^T
__global__ __launch_bounds__(256) void prep(
    const float* __restrict__ H, const float* __restrict__ Wqkv, const float* __restrict__ Wproj,
    u16* __restrict__ Hb, u16* __restrict__ WqkvT, u16* __restrict__ WprojT)
{
  __shared__ u16 tile[32][33];
  const int bid = blockIdx.x, tid = threadIdx.x;
  if (bid < 4096) {
    int i = (bid*256 + tid)*4;
    float4 v = *(const float4*)(H + i);
    ushort4 o;
    o.x = f2bf(v.x); o.y = f2bf(v.y); o.z = f2bf(v.z); o.w = f2bf(v.w);
    *(ushort4*)(Hb + i) = o;
    return;
  }
  const float* in; u16* out; int R, C, bx, by;
  if (bid < 7168) { int t = bid-4096; in=Wqkv; out=WqkvT; R=1024; C=3072; bx=t%96; by=t/96; }
  else            { int t = bid-7168; in=Wproj; out=WprojT; R=1024; C=1024; bx=t%32; by=t/32; }
  int bc = bx*32, br = by*32;
  int tx = tid & 31, ty = tid >> 5;
  #pragma unroll
  for (int i=ty;i<32;i+=8) tile[i][tx] = f2bf(in[(size_t)(br+i)*C + bc + tx]);
  __syncthreads();
  #pragma unroll
  for (int i=ty;i<32;i+=8) out[(size_t)(bc+i)*R + br + tx] = tile[tx][i];
}

// ---------------- QKV GEMM with fused bias + RoPE + split epilogue + fused V-transpose ----------------
// r13 version (measured best). Q/K: direct segment-coalesced stores. V: swizzled LDS
// tile + key-permuted gather-stores to VT [h][64][4096].
__global__ __launch_bounds__(256) void gemm_qkv_rope(
    const u16* __restrict__ A, const u16* __restrict__ Bt,
    const float* __restrict__ bias, const float* __restrict__ cosb, const float* __restrict__ sinb,
    u16* __restrict__ Qo, u16* __restrict__ Ko, u16* __restrict__ Vt)
{
  constexpr int K = 1024;
  __shared__ __align__(16) u16 smem[128*128];   // As = [0,8192), Bs = [8192,16384)
  u16* const As = smem;
  u16* const Bs = smem + 128*64;
  const int m0 = blockIdx.y*128, n0 = blockIdx.x*128;
  const int tid = threadIdx.x, wave = tid>>6, lane = tid&63;
  const int wr = (wave>>1)*64, wc = (wave&1)*64;
  const int ml = lane&15, quad = lane>>4;
  const int lrow8 = lane>>3, lchk = lane&7;
  const int swzg = (lchk ^ lrow8)*8;
  const u16* gA[4]; u16* lA[4];
  const u16* gB[4]; u16* lB[4];
  #pragma unroll
  for (int t=0;t<4;t++){
    gA[t] = A  + (size_t)(m0 + wave*32 + t*8 + lrow8)*K + swzg;
    lA[t] = &As[(wave*32 + t*8)*64];
    gB[t] = Bt + (size_t)(n0 + wave*32 + t*8 + lrow8)*K + swzg;
    lB[t] = &Bs[(wave*32 + t*8)*64];
  }
  f32x4 acc[4][4] = {};
  const int rch0 = ( quad     ^ (ml&7))*8;
  const int rch1 = ((quad|4) ^ (ml&7))*8;
  for (int k0=0; k0<K; k0+=64) {
    #pragma unroll
    for (int t=0;t<4;t++){ async_cp16(gA[t]+k0, lA[t]); async_cp16(gB[t]+k0, lB[t]); }
    __syncthreads();
    #pragma unroll
    for (int kk=0;kk<2;kk++){
      const int rc = kk ? rch1 : rch0;
      bf16x8 af[4], bfr[4];
      #pragma unroll
      for (int i=0;i<4;i++)  af[i]  = *(const bf16x8*)&As[(wr+i*16+ml)*64 + rc];
      #pragma unroll
      for (int j=0;j<4;j++) bfr[j] = *(const bf16x8*)&Bs[(wc+j*16+ml)*64 + rc];
      #pragma unroll
      for (int i=0;i<4;i++)
        #pragma unroll
        for (int j=0;j<4;j++)
          acc[i][j] = MFMA(af[i], bfr[j], acc[i][j]);
    }
    __syncthreads();
  }
  const int region = n0 >> 10;   // 0=Q, 1=K, 2=V (block-uniform)
  if (region == 2) {
    // ---- phase 1: bias + cvt into swizzled LDS tile [t=0..127][d2=0..127] ----
    #pragma unroll
    for (int j=0;j<4;j++){
      int d2 = wc + j*16 + ml;             // local col 0..127
      float bv = bias[n0 + d2];
      #pragma unroll
      for (int i=0;i<4;i++){
        int t0 = wr + i*16 + quad*4;
        #pragma unroll
        for (int r=0;r<4;r++){
          int t = t0 + r;
          int c = (d2 >> 3) ^ (t & 15);
          smem[t*128 + c*8 + (d2 & 7)] = f2bf(acc[i][j][r] + bv);
        }
      }
    }
    __syncthreads();
    // ---- phase 2: coalesced VT write with key-permutation ----
    const int hbase = (n0 - 2048) >> 6;
    const int tx = tid & 31, ty = tid >> 5;
    const int tlog32 = ((tx>>2)&1)*16 + (tx>>3)*4 + (tx&3);
    #pragma unroll
    for (int ii=0; ii<16; ii++){
      int d2 = ty + ii*8;
      int hh = hbase + (d2 >> 6);
      int dd = d2 & 63;
      u16* vrow = Vt + ((size_t)hh*64 + dd)*4096 + m0;
      #pragma unroll
      for (int tq=0; tq<4; tq++){
        int t_src = tq*32 + tlog32;
        int c = (d2 >> 3) ^ (t_src & 15);
        vrow[tq*32 + tx] = smem[t_src*128 + c*8 + (d2 & 7)];
      }
    }
  } else {
    u16* dst = region ? Ko : Qo;
    const float qs = region ? 1.0f : 0.125f*1.44269504f;
    #pragma unroll
    for (int j=0;j<4;j++){
      int col = n0 + wc + j*16 + ml;
      int dloc = col & 63, hh = (col & 1023) >> 6;
      float bv  = bias[col];
      float bvp = bias[col ^ 32];
      float sgn = (dloc < 32) ? -1.f : 1.f;
      #pragma unroll
      for (int i=0;i<4;i++){
        int row0 = m0 + wr + i*16 + quad*4;
        #pragma unroll
        for (int r=0;r<4;r++){
          int t = row0 + r;
          float c = cosb[t*64 + dloc], s = sinb[t*64 + dloc];
          float val = acc[i][j][r]   + bv;
          float par = acc[i][j^2][r] + bvp;
          dst[((size_t)hh*4096 + t)*64 + dloc] = f2bf((val*c + sgn*par*s)*qs);
        }
      }
    }
  }
}

// ---------------- generic GEMM (proj): C[M][N] = A @ Bt^T + bias ----------------
template<int BN, typename OutT>
__global__ __launch_bounds__(256) void gemm_bt_bias(
    const u16* __restrict__ A, const u16* __restrict__ Bt,
    const float* __restrict__ bias, OutT* __restrict__ C,
    int M, int N, int K)
{
  __shared__ __align__(16) u16 As[128*64];
  __shared__ __align__(16) u16 Bs[BN*64];
  const int m0 = blockIdx.y*128, n0 = blockIdx.x*BN;
  const int tid = threadIdx.x, wave = tid>>6, lane = tid&63;
  const int wr = (wave>>1)*64, wc = (wave&1)*(BN/2);
  const int ml = lane&15, quad = lane>>4;
  const int lrow8 = lane>>3, lchk = lane&7;
  const int swzg = (lchk ^ lrow8)*8;
  const u16* gA[4]; u16* lA[4];
  #pragma unroll
  for (int t=0;t<4;t++){
    gA[t] = A + (size_t)(m0 + wave*32 + t*8 + lrow8)*K + swzg;
    lA[t] = &As[(wave*32 + t*8)*64];
  }
  constexpr int BI = BN/32;
  const u16* gB[BI]; u16* lB[BI];
  #pragma unroll
  for (int t=0;t<BI;t++){
    gB[t] = Bt + (size_t)(n0 + wave*(BN/4) + t*8 + lrow8)*K + swzg;
    lB[t] = &Bs[(wave*(BN/4) + t*8)*64];
  }
  constexpr int NJ = BN/32;
  f32x4 acc[4][NJ] = {};
  const int rch0 = ( quad     ^ (ml&7))*8;
  const int rch1 = ((quad|4) ^ (ml&7))*8;
  for (int k0=0; k0<K; k0+=64) {
    #pragma unroll
    for (int t=0;t<4;t++)  async_cp16(gA[t]+k0, lA[t]);
    #pragma unroll
    for (int t=0;t<BI;t++) async_cp16(gB[t]+k0, lB[t]);
    __syncthreads();
    #pragma unroll
    for (int kk=0;kk<2;kk++){
      const int rc = kk ? rch1 : rch0;
      bf16x8 af[4], bfr[NJ];
      #pragma unroll
      for (int i=0;i<4;i++)  af[i]  = *(const bf16x8*)&As[(wr+i*16+ml)*64 + rc];
      #pragma unroll
      for (int j=0;j<NJ;j++) bfr[j] = *(const bf16x8*)&Bs[(wc+j*16+ml)*64 + rc];
      #pragma unroll
      for (int i=0;i<4;i++)
        #pragma unroll
        for (int j=0;j<NJ;j++)
          acc[i][j] = MFMA(af[i], bfr[j], acc[i][j]);
    }
    __syncthreads();
  }
  #pragma unroll
  for (int j=0;j<NJ;j++){
    int col = n0 + wc + j*16 + ml;
    float bv = bias[col];
    #pragma unroll
    for (int i=0;i<4;i++){
      int row0 = m0 + wr + i*16 + quad*4;
      #pragma unroll
      for (int r=0;r<4;r++){
        float val = acc[i][j][r] + bv;
        if constexpr (std::is_same_v<OutT, float>)
          C[(size_t)(row0+r)*N + col] = val;
        else
          C[(size_t)(row0+r)*N + col] = f2bf(val);
      }
    }
  }
}

// ---------------- flash attention r17: 32 q/wave, K-split x2, 128-key staging ----------------
// r13 inner math; barriers halved by staging TWO 64-key sub-tiles per sync pair
// (8 async loads batched -> deeper MLP; 32 instead of 64 barriers/block).
// LDS 32 KB, still 4 blocks/CU (128 KB < 160 KB). No setprio (r3); registers
// unchanged (halves computed sequentially with the same temporaries).
__global__ __launch_bounds__(256,4) void flash_attn(
    const u16* __restrict__ Q, const u16* __restrict__ Kg, const u16* __restrict__ VT,
    u16* __restrict__ O0, u16* __restrict__ O1, float* __restrict__ Lpart)
{
  constexpr int SEQ=4096, HALF=2048;
  __shared__ __align__(16) u16 Ks[2][64*64];
  __shared__ __align__(16) u16 Vs[2][64*64];
  const int lin = blockIdx.x;
  const int idx = (lin & 7)*128 + (lin >> 3);
  const int qt = idx & 31, h = (idx >> 5) & 15, ks = idx >> 9;
  const int tid=threadIdx.x, wave=tid>>6, lane=tid&63;
  const int ml=lane&15, quad=lane>>4;
  const int qbase = qt*128 + wave*32;
  bf16x8 qf[2][2];
  #pragma unroll
  for (int qi=0; qi<2; qi++){
    const u16* qp = Q + ((size_t)h*SEQ + qbase + qi*16 + ml)*64;
    qf[qi][0] = *(const bf16x8*)(qp + quad*8);
    qf[qi][1] = *(const bf16x8*)(qp + 32 + quad*8);
  }
  const bf16x8 ones = {0x3F80,0x3F80,0x3F80,0x3F80,0x3F80,0x3F80,0x3F80,0x3F80};
  f32x4 o[2][4] = {};
  f32x4 accsum[2] = {};
  const int lrow8 = lane>>3, lchk = lane&7;
  const int swzg = (lchk ^ lrow8)*8;
  const u16* kgl = Kg + (size_t)h*SEQ*64 + (size_t)(ks*HALF + wave*16 + lrow8)*64 + swzg;
  const u16* vgl = VT + (size_t)h*64*SEQ + (size_t)(wave*16 + lrow8)*SEQ + ks*HALF + swzg;
  const int swzA = ( quad     ^ (ml&7))*8;
  const int swzB = ((quad^4) ^ (ml&7))*8;

  u16* const kd0 = &Ks[0][(wave*16)*64];
  u16* const kd1 = &Ks[0][(wave*16+8)*64];
  u16* const kd2 = &Ks[1][(wave*16)*64];
  u16* const kd3 = &Ks[1][(wave*16+8)*64];
  u16* const vd0 = &Vs[0][(wave*16)*64];
  u16* const vd1 = &Vs[0][(wave*16+8)*64];
  u16* const vd2 = &Vs[1][(wave*16)*64];
  u16* const vd3 = &Vs[1][(wave*16+8)*64];

  for (int k0=0;k0<HALF;k0+=128) {
    // stage both 64-key sub-tiles (8 loads batched)
    async_cp16(kgl + (size_t)k0*64,            kd0);
    async_cp16(kgl + (size_t)k0*64 + 512,      kd1);
    async_cp16(kgl + (size_t)(k0+64)*64,       kd2);
    async_cp16(kgl + (size_t)(k0+64)*64 + 512, kd3);
    async_cp16(vgl + k0,                       vd0);
    async_cp16(vgl + 8*SEQ + k0,               vd1);
    async_cp16(vgl + k0 + 64,                  vd2);
    async_cp16(vgl + 8*SEQ + k0 + 64,          vd3);
    __syncthreads();
    #pragma unroll
    for (int half=0; half<2; half++){
      const u16* Kc = &Ks[half][0];
      const u16* Vc = &Vs[half][0];
      f32x4 s[2][4];
      #pragma unroll
      for (int kb=0;kb<4;kb++){
        bf16x8 kf0 = *(const bf16x8*)&Kc[(kb*16+ml)*64 + swzA];
        bf16x8 kf1 = *(const bf16x8*)&Kc[(kb*16+ml)*64 + swzB];
        f32x4 z0={0,0,0,0}, z1={0,0,0,0};
        z0 = MFMA(kf0, qf[0][0], z0); s[0][kb] = MFMA(kf1, qf[0][1], z0);
        z1 = MFMA(kf0, qf[1][0], z1); s[1][kb] = MFMA(kf1, qf[1][1], z1);
      }
      bf16x8 vf[4][2];
      #pragma unroll
      for (int db=0;db<4;db++){
        vf[db][0] = *(const bf16x8*)&Vc[(db*16+ml)*64 + swzA];
        vf[db][1] = *(const bf16x8*)&Vc[(db*16+ml)*64 + swzB];
      }
      #pragma unroll
      for (int qi=0; qi<2; qi++)
        #pragma unroll
        for (int p=0;p<2;p++){
          float e0 = EXP2(s[qi][2*p][0]),   e1 = EXP2(s[qi][2*p][1]);
          float e2 = EXP2(s[qi][2*p][2]),   e3 = EXP2(s[qi][2*p][3]);
          float e4 = EXP2(s[qi][2*p+1][0]), e5 = EXP2(s[qi][2*p+1][1]);
          float e6 = EXP2(s[qi][2*p+1][2]), e7 = EXP2(s[qi][2*p+1][3]);
          union { uint4 u; bf16x8 v; } pf;
          pf.u.x = pkbf(e0,e1); pf.u.y = pkbf(e2,e3);
          pf.u.z = pkbf(e4,e5); pf.u.w = pkbf(e6,e7);
          accsum[qi] = MFMA(ones, pf.v, accsum[qi]);
          #pragma unroll
          for (int db=0;db<4;db++)
            o[qi][db] = MFMA(vf[db][p], pf.v, o[qi][db]);
        }
    }
    __syncthreads();
  }
  u16* op = ks ? O1 : O0;
  #pragma unroll
  for (int qi=0;qi<2;qi++){
    size_t rb = (size_t)(qbase + qi*16 + ml)*1024 + h*64;
    #pragma unroll
    for (int db=0;db<4;db++){
      uint2 w;
      w.x = pkbf(o[qi][db][0], o[qi][db][1]);
      w.y = pkbf(o[qi][db][2], o[qi][db][3]);
      *(uint2*)&op[rb + db*16 + quad*4] = w;
    }
  }
  if (quad==0){
    float* lp = Lpart + (size_t)ks*65536 + (size_t)h*4096 + qbase;
    lp[ml]    = accsum[0][0];
    lp[16+ml] = accsum[1][0];
  }
}

// ---------------- combine the two K-split partials, normalize, emit bf16 AO ----------------
__global__ __launch_bounds__(256) void combine_softmax2(
    const u16* __restrict__ O0, const u16* __restrict__ O1,
    const float* __restrict__ L, u16* __restrict__ AO)
{
  int i = (blockIdx.x*256 + threadIdx.x)*4;
  int row = i >> 10, col = i & 1023, h = col >> 6;
  int li = h*4096 + row;
  float inv = 1.f/(L[li] + L[li+65536]);
  ushort4 a = *(const ushort4*)(O0+i);
  ushort4 b = *(const ushort4*)(O1+i);
  ushort4 o;
  o.x = f2bf((bf2f(a.x)+bf2f(b.x))*inv);
  o.y = f2bf((bf2f(a.y)+bf2f(b.y))*inv);
  o.z = f2bf((bf2f(a.z)+bf2f(b.z))*inv);
  o.w = f2bf((bf2f(a.w)+bf2f(b.w))*inv);
  *(ushort4*)(AO+i) = o;
}

extern "C" void kernel_launch(void* const* d_in, const int* in_sizes, int n_in,
                              void* d_out, int out_size, void* d_ws, size_t ws_size,
                              hipStream_t stream)
{
  (void)in_sizes; (void)n_in; (void)out_size; (void)ws_size;
  const float* H     = (const float*)d_in[0];
  // d_in[1] = cu_seqlens (unused by reference)
  const float* cosb  = (const float*)d_in[2];
  const float* sinb  = (const float*)d_in[3];
  const float* Wqkv  = (const float*)d_in[4];
  const float* bqkv  = (const float*)d_in[5];
  const float* Wproj = (const float*)d_in[6];
  const float* bproj = (const float*)d_in[7];
  float* out = (float*)d_out;
  char* ws = (char*)d_ws;
  // 52 MiB layout. Lifetimes: Hb dead after gemm -> Opart0; Qb dead after flash -> AO.
  float* Lpart  = (float*)(ws + 0);         // [2][16][4096] f32, 0.5 MB (1 MB region)
  u16*   WprojT = (u16*)(ws + 2097152);     // 2 MB
  u16*   Hb     = (u16*)(ws + 4194304);     // 8 MB
  u16*   Opart0 = (u16*)(ws + 4194304);     //   (reuses Hb, dead after gemm)
  u16*   Qb     = (u16*)(ws + 12582912);    // 8 MB
  u16*   AO     = (u16*)(ws + 12582912);    //   (reuses Qb, dead after flash)
  u16*   Kb     = (u16*)(ws + 20971520);    // 8 MB
  u16*   VTb    = (u16*)(ws + 29360128);    // 8 MB
  u16*   WqkvT  = (u16*)(ws + 37748736);    // 6 MB
  u16*   Opart1 = (u16*)(ws + 44040192);    // 8 MB (ends 52 MB)

  hipLaunchKernelGGL(prep, dim3(8192), dim3(256), 0, stream, H, Wqkv, Wproj, Hb, WqkvT, WprojT);
  hipLaunchKernelGGL(gemm_qkv_rope, dim3(24,32), dim3(256), 0, stream,
                     Hb, WqkvT, bqkv, cosb, sinb, Qb, Kb, VTb);
  hipLaunchKernelGGL(flash_attn, dim3(1024), dim3(256), 0, stream, Qb, Kb, VTb,
                     Opart0, Opart1, Lpart);
  hipLaunchKernelGGL(combine_softmax2, dim3(4096), dim3(256), 0, stream,
                     Opart0, Opart1, Lpart, AO);
  hipLaunchKernelGGL((gemm_bt_bias<64,float>), dim3(16,32), dim3(256), 0, stream,
                     AO, WprojT, bproj, out, 4096, 1024, 1024);
}

// Round 12
// 233.768 us; speedup vs baseline: 1.1033x; 1.1033x over previous
//
#include <hip/hip_runtime.h>
#include <type_traits>

typedef short bf16x8 __attribute__((ext_vector_type(8)));
typedef float f32x4  __attribute__((ext_vector_type(4)));
typedef unsigned short u16;

#define MFMA(a,b,c) __builtin_amdgcn_mfma_f32_16x16x32_bf16((a),(b),(c),0,0,0)

__device__ __forceinline__ float bf2f(u16 u){ unsigned x=((unsigned)u)<<16; return __builtin_bit_cast(float,x); }
__device__ __forceinline__ u16 f2bf(float f){ unsigned x=__builtin_bit_cast(unsigned,f); x += 0x7fffu + ((x>>16)&1u); return (u16)(x>>16); }

#if __has_builtin(__builtin_amdgcn_cvt_pk_bf16_f32)
typedef __bf16 hwbf2 __attribute__((ext_vector_type(2)));
__device__ __forceinline__ unsigned pkbf(float a, float b){
  hwbf2 r = __builtin_amdgcn_cvt_pk_bf16_f32(a, b);   // lo=a, hi=b, RNE
  return __builtin_bit_cast(unsigned, r);
}
#else
__device__ __forceinline__ unsigned pkbf(float a, float b){
  unsigned ua = __builtin_bit_cast(unsigned, a), ub = __builtin_bit_cast(unsigned, b);
  ua += 0x7fffu + ((ua>>16)&1u);
  ub += 0x7fffu + ((ub>>16)&1u);
  return __builtin_amdgcn_perm(ub, ua, 0x07060302u);
}
#endif

#if __has_builtin(__builtin_amdgcn_exp2f)
#define EXP2(x) __builtin_amdgcn_exp2f(x)
#else
#define EXP2(x) exp2f(x)
#endif

__device__ __forceinline__ void async_cp16(const u16* g, u16* l){
  __builtin_amdgcn_global_load_lds((const __attribute__((address_space(1))) void*)g,
                                   (__attribute__((address_space(3))) void*)l, 16, 0, 0);
}

// ---------------- fused prep: cvt H->bf16, transpose Wqkv & Wproj to bf16 ----------------
// flat grid 8192: [0,4096) cvt; [4096,7168) Wqkv^T; [7168,8192) Wproj^T
__global__ __launch_bounds__(256) void prep(
    const float* __restrict__ H, const float* __restrict__ Wqkv, const float* __restrict__ Wproj,
    u16* __restrict__ Hb, u16* __restrict__ WqkvT, u16* __restrict__ WprojT)
{
  __shared__ u16 tile[32][33];
  const int bid = blockIdx.x, tid = threadIdx.x;
  if (bid < 4096) {
    int i = (bid*256 + tid)*4;
    float4 v = *(const float4*)(H + i);
    ushort4 o;
    o.x = f2bf(v.x); o.y = f2bf(v.y); o.z = f2bf(v.z); o.w = f2bf(v.w);
    *(ushort4*)(Hb + i) = o;
    return;
  }
  const float* in; u16* out; int R, C, bx, by;
  if (bid < 7168) { int t = bid-4096; in=Wqkv; out=WqkvT; R=1024; C=3072; bx=t%96; by=t/96; }
  else            { int t = bid-7168; in=Wproj; out=WprojT; R=1024; C=1024; bx=t%32; by=t/32; }
  int bc = bx*32, br = by*32;
  int tx = tid & 31, ty = tid >> 5;
  #pragma unroll
  for (int i=ty;i<32;i+=8) tile[i][tx] = f2bf(in[(size_t)(br+i)*C + bc + tx]);
  __syncthreads();
  #pragma unroll
  for (int i=ty;i<32;i+=8) out[(size_t)(bc+i)*R + br + tx] = tile[tx][i];
}

// ---------------- QKV GEMM with fused bias + RoPE + split epilogue + fused V-transpose ----------------
// C = Hb[4096][1024] @ WqkvT[3072][1024]^T + b; then RoPE(Q,K) -> Qo/Ko [h][t][64]
// (Q pre-scaled 0.125*log2e); V region writes VT [h][64][4096] DIRECTLY with the
// key-permutation baked in: within each 32-key group physical col p holds logical
// key ((p>>2)&1)*16 + (p>>3)*4 + (p&3).
__global__ __launch_bounds__(256) void gemm_qkv_rope(
    const u16* __restrict__ A, const u16* __restrict__ Bt,
    const float* __restrict__ bias, const float* __restrict__ cosb, const float* __restrict__ sinb,
    u16* __restrict__ Qo, u16* __restrict__ Ko, u16* __restrict__ Vt)
{
  constexpr int K = 1024;
  __shared__ __align__(16) u16 smem[128*128];   // As = [0,8192), Bs = [8192,16384)
  u16* const As = smem;
  u16* const Bs = smem + 128*64;
  const int m0 = blockIdx.y*128, n0 = blockIdx.x*128;
  const int tid = threadIdx.x, wave = tid>>6, lane = tid&63;
  const int wr = (wave>>1)*64, wc = (wave&1)*64;
  const int ml = lane&15, quad = lane>>4;
  const int lrow8 = lane>>3, lchk = lane&7;
  const int swzg = (lchk ^ lrow8)*8;
  const u16* gA[4]; u16* lA[4];
  const u16* gB[4]; u16* lB[4];
  #pragma unroll
  for (int t=0;t<4;t++){
    gA[t] = A  + (size_t)(m0 + wave*32 + t*8 + lrow8)*K + swzg;
    lA[t] = &As[(wave*32 + t*8)*64];
    gB[t] = Bt + (size_t)(n0 + wave*32 + t*8 + lrow8)*K + swzg;
    lB[t] = &Bs[(wave*32 + t*8)*64];
  }
  f32x4 acc[4][4] = {};
  const int rch0 = ( quad     ^ (ml&7))*8;
  const int rch1 = ((quad|4) ^ (ml&7))*8;
  for (int k0=0; k0<K; k0+=64) {
    #pragma unroll
    for (int t=0;t<4;t++){ async_cp16(gA[t]+k0, lA[t]); async_cp16(gB[t]+k0, lB[t]); }
    __syncthreads();
    #pragma unroll
    for (int kk=0;kk<2;kk++){
      const int rc = kk ? rch1 : rch0;
      bf16x8 af[4], bfr[4];
      #pragma unroll
      for (int i=0;i<4;i++)  af[i]  = *(const bf16x8*)&As[(wr+i*16+ml)*64 + rc];
      #pragma unroll
      for (int j=0;j<4;j++) bfr[j] = *(const bf16x8*)&Bs[(wc+j*16+ml)*64 + rc];
      #pragma unroll
      for (int i=0;i<4;i++)
        #pragma unroll
        for (int j=0;j<4;j++)
          acc[i][j] = MFMA(af[i], bfr[j], acc[i][j]);
    }
    __syncthreads();
  }
  const int region = n0 >> 10;   // 0=Q, 1=K, 2=V (block-uniform)
  if (region == 2) {
    // ---- phase 1: bias + cvt into swizzled LDS tile [t=0..127][d2=0..127] ----
    #pragma unroll
    for (int j=0;j<4;j++){
      int d2 = wc + j*16 + ml;             // local col 0..127
      float bv = bias[n0 + d2];
      #pragma unroll
      for (int i=0;i<4;i++){
        int t0 = wr + i*16 + quad*4;
        #pragma unroll
        for (int r=0;r<4;r++){
          int t = t0 + r;
          int c = (d2 >> 3) ^ (t & 15);
          smem[t*128 + c*8 + (d2 & 7)] = f2bf(acc[i][j][r] + bv);
        }
      }
    }
    __syncthreads();
    // ---- phase 2: coalesced VT write with key-permutation ----
    const int hbase = (n0 - 2048) >> 6;
    const int tx = tid & 31, ty = tid >> 5;
    const int tlog32 = ((tx>>2)&1)*16 + (tx>>3)*4 + (tx&3);
    #pragma unroll
    for (int ii=0; ii<16; ii++){
      int d2 = ty + ii*8;
      int hh = hbase + (d2 >> 6);
      int dd = d2 & 63;
      u16* vrow = Vt + ((size_t)hh*64 + dd)*4096 + m0;
      #pragma unroll
      for (int tq=0; tq<4; tq++){
        int t_src = tq*32 + tlog32;
        int c = (d2 >> 3) ^ (t_src & 15);
        vrow[tq*32 + tx] = smem[t_src*128 + c*8 + (d2 & 7)];
      }
    }
  } else {
    u16* dst = region ? Ko : Qo;
    const float qs = region ? 1.0f : 0.125f*1.44269504f;
    #pragma unroll
    for (int j=0;j<4;j++){
      int col = n0 + wc + j*16 + ml;
      int dloc = col & 63, hh = (col & 1023) >> 6;
      float bv  = bias[col];
      float bvp = bias[col ^ 32];
      float sgn = (dloc < 32) ? -1.f : 1.f;
      #pragma unroll
      for (int i=0;i<4;i++){
        int row0 = m0 + wr + i*16 + quad*4;
        #pragma unroll
        for (int r=0;r<4;r++){
          int t = row0 + r;
          float c = cosb[t*64 + dloc], s = sinb[t*64 + dloc];
          float val = acc[i][j][r]   + bv;
          float par = acc[i][j^2][r] + bvp;
          dst[((size_t)hh*4096 + t)*64 + dloc] = f2bf((val*c + sgn*par*s)*qs);
        }
      }
    }
  }
}

// ---------------- generic GEMM (proj): C[M][N] = A @ Bt^T + bias ----------------
template<int BN, typename OutT>
__global__ __launch_bounds__(256) void gemm_bt_bias(
    const u16* __restrict__ A, const u16* __restrict__ Bt,
    const float* __restrict__ bias, OutT* __restrict__ C,
    int M, int N, int K)
{
  __shared__ __align__(16) u16 As[128*64];
  __shared__ __align__(16) u16 Bs[BN*64];
  const int m0 = blockIdx.y*128, n0 = blockIdx.x*BN;
  const int tid = threadIdx.x, wave = tid>>6, lane = tid&63;
  const int wr = (wave>>1)*64, wc = (wave&1)*(BN/2);
  const int ml = lane&15, quad = lane>>4;
  const int lrow8 = lane>>3, lchk = lane&7;
  const int swzg = (lchk ^ lrow8)*8;
  const u16* gA[4]; u16* lA[4];
  #pragma unroll
  for (int t=0;t<4;t++){
    gA[t] = A + (size_t)(m0 + wave*32 + t*8 + lrow8)*K + swzg;
    lA[t] = &As[(wave*32 + t*8)*64];
  }
  constexpr int BI = BN/32;
  const u16* gB[BI]; u16* lB[BI];
  #pragma unroll
  for (int t=0;t<BI;t++){
    gB[t] = Bt + (size_t)(n0 + wave*(BN/4) + t*8 + lrow8)*K + swzg;
    lB[t] = &Bs[(wave*(BN/4) + t*8)*64];
  }
  constexpr int NJ = BN/32;
  f32x4 acc[4][NJ] = {};
  const int rch0 = ( quad     ^ (ml&7))*8;
  const int rch1 = ((quad|4) ^ (ml&7))*8;
  for (int k0=0; k0<K; k0+=64) {
    #pragma unroll
    for (int t=0;t<4;t++)  async_cp16(gA[t]+k0, lA[t]);
    #pragma unroll
    for (int t=0;t<BI;t++) async_cp16(gB[t]+k0, lB[t]);
    __syncthreads();
    #pragma unroll
    for (int kk=0;kk<2;kk++){
      const int rc = kk ? rch1 : rch0;
      bf16x8 af[4], bfr[NJ];
      #pragma unroll
      for (int i=0;i<4;i++)  af[i]  = *(const bf16x8*)&As[(wr+i*16+ml)*64 + rc];
      #pragma unroll
      for (int j=0;j<NJ;j++) bfr[j] = *(const bf16x8*)&Bs[(wc+j*16+ml)*64 + rc];
      #pragma unroll
      for (int i=0;i<4;i++)
        #pragma unroll
        for (int j=0;j<NJ;j++)
          acc[i][j] = MFMA(af[i], bfr[j], acc[i][j]);
    }
    __syncthreads();
  }
  #pragma unroll
  for (int j=0;j<NJ;j++){
    int col = n0 + wc + j*16 + ml;
    float bv = bias[col];
    #pragma unroll
    for (int i=0;i<4;i++){
      int row0 = m0 + wr + i*16 + quad*4;
      #pragma unroll
      for (int r=0;r<4;r++){
        float val = acc[i][j][r] + bv;
        if constexpr (std::is_same_v<OutT, float>)
          C[(size_t)(row0+r)*N + col] = val;
        else
          C[(size_t)(row0+r)*N + col] = f2bf(val);
      }
    }
  }
}

// ---------------- flash attention r13: 32 q/wave, K-split x2 ----------------
// 32q/wave = best MFMA-per-LDS-read economy (r12 A/B); grid 1024 = 16 waves/CU.
// XCD chunk: each XCD holds 4 heads x 2048 keys K+V = 2 MB, L2-resident.
// No setprio (r3); single-buffer (r8/r9 null); compute body appears EXACTLY ONCE
// (r8/r17: any 2x unroll of it spills -> WRITE_SIZE blows up 4x). Issue-bound at
// ~90% combined MfmaUtil+VALUBusy — structural floor for this algorithm.
__global__ __launch_bounds__(256,4) void flash_attn(
    const u16* __restrict__ Q, const u16* __restrict__ Kg, const u16* __restrict__ VT,
    u16* __restrict__ O0, u16* __restrict__ O1, float* __restrict__ Lpart)
{
  constexpr int SEQ=4096, HALF=2048;
  __shared__ __align__(16) u16 Ks[64*64];
  __shared__ __align__(16) u16 Vs[64*64];
  const int lin = blockIdx.x;
  const int idx = (lin & 7)*128 + (lin >> 3);
  const int qt = idx & 31, h = (idx >> 5) & 15, ks = idx >> 9;
  const int tid=threadIdx.x, wave=tid>>6, lane=tid&63;
  const int ml=lane&15, quad=lane>>4;
  const int qbase = qt*128 + wave*32;
  bf16x8 qf[2][2];
  #pragma unroll
  for (int qi=0; qi<2; qi++){
    const u16* qp = Q + ((size_t)h*SEQ + qbase + qi*16 + ml)*64;
    qf[qi][0] = *(const bf16x8*)(qp + quad*8);
    qf[qi][1] = *(const bf16x8*)(qp + 32 + quad*8);
  }
  const bf16x8 ones = {0x3F80,0x3F80,0x3F80,0x3F80,0x3F80,0x3F80,0x3F80,0x3F80};
  f32x4 o[2][4] = {};
  f32x4 accsum[2] = {};
  const int lrow8 = lane>>3, lchk = lane&7;
  const int swzg = (lchk ^ lrow8)*8;
  const u16* kgl = Kg + (size_t)h*SEQ*64 + (size_t)(ks*HALF + wave*16 + lrow8)*64 + swzg;
  const u16* vgl = VT + (size_t)h*64*SEQ + (size_t)(wave*16 + lrow8)*SEQ + ks*HALF + swzg;
  u16* kl0 = &Ks[(wave*16  )*64];
  u16* kl1 = &Ks[(wave*16+8)*64];
  u16* vl0 = &Vs[(wave*16  )*64];
  u16* vl1 = &Vs[(wave*16+8)*64];
  const int swzA = ( quad     ^ (ml&7))*8;
  const int swzB = ((quad^4) ^ (ml&7))*8;

  for (int k0=0;k0<HALF;k0+=64) {
    async_cp16(kgl + (size_t)k0*64,       kl0);
    async_cp16(kgl + (size_t)k0*64 + 512, kl1);
    async_cp16(vgl + k0,                  vl0);
    async_cp16(vgl + 8*SEQ + k0,          vl1);
    __syncthreads();
    f32x4 s[2][4];
    #pragma unroll
    for (int kb=0;kb<4;kb++){
      bf16x8 kf0 = *(const bf16x8*)&Ks[(kb*16+ml)*64 + swzA];
      bf16x8 kf1 = *(const bf16x8*)&Ks[(kb*16+ml)*64 + swzB];
      f32x4 z0={0,0,0,0}, z1={0,0,0,0};
      z0 = MFMA(kf0, qf[0][0], z0); s[0][kb] = MFMA(kf1, qf[0][1], z0);
      z1 = MFMA(kf0, qf[1][0], z1); s[1][kb] = MFMA(kf1, qf[1][1], z1);
    }
    bf16x8 vf[4][2];
    #pragma unroll
    for (int db=0;db<4;db++){
      vf[db][0] = *(const bf16x8*)&Vs[(db*16+ml)*64 + swzA];
      vf[db][1] = *(const bf16x8*)&Vs[(db*16+ml)*64 + swzB];
    }
    #pragma unroll
    for (int qi=0; qi<2; qi++)
      #pragma unroll
      for (int p=0;p<2;p++){
        float e0 = EXP2(s[qi][2*p][0]),   e1 = EXP2(s[qi][2*p][1]);
        float e2 = EXP2(s[qi][2*p][2]),   e3 = EXP2(s[qi][2*p][3]);
        float e4 = EXP2(s[qi][2*p+1][0]), e5 = EXP2(s[qi][2*p+1][1]);
        float e6 = EXP2(s[qi][2*p+1][2]), e7 = EXP2(s[qi][2*p+1][3]);
        union { uint4 u; bf16x8 v; } pf;
        pf.u.x = pkbf(e0,e1); pf.u.y = pkbf(e2,e3);
        pf.u.z = pkbf(e4,e5); pf.u.w = pkbf(e6,e7);
        accsum[qi] = MFMA(ones, pf.v, accsum[qi]);
        #pragma unroll
        for (int db=0;db<4;db++)
          o[qi][db] = MFMA(vf[db][p], pf.v, o[qi][db]);
      }
    __syncthreads();
  }
  u16* op = ks ? O1 : O0;
  #pragma unroll
  for (int qi=0;qi<2;qi++){
    size_t rb = (size_t)(qbase + qi*16 + ml)*1024 + h*64;
    #pragma unroll
    for (int db=0;db<4;db++){
      uint2 w;
      w.x = pkbf(o[qi][db][0], o[qi][db][1]);
      w.y = pkbf(o[qi][db][2], o[qi][db][3]);
      *(uint2*)&op[rb + db*16 + quad*4] = w;
    }
  }
  if (quad==0){
    float* lp = Lpart + (size_t)ks*65536 + (size_t)h*4096 + qbase;
    lp[ml]    = accsum[0][0];
    lp[16+ml] = accsum[1][0];
  }
}

// ---------------- combine the two K-split partials, normalize, emit bf16 AO ----------------
__global__ __launch_bounds__(256) void combine_softmax2(
    const u16* __restrict__ O0, const u16* __restrict__ O1,
    const float* __restrict__ L, u16* __restrict__ AO)
{
  int i = (blockIdx.x*256 + threadIdx.x)*4;
  int row = i >> 10, col = i & 1023, h = col >> 6;
  int li = h*4096 + row;
  float inv = 1.f/(L[li] + L[li+65536]);
  ushort4 a = *(const ushort4*)(O0+i);
  ushort4 b = *(const ushort4*)(O1+i);
  ushort4 o;
  o.x = f2bf((bf2f(a.x)+bf2f(b.x))*inv);
  o.y = f2bf((bf2f(a.y)+bf2f(b.y))*inv);
  o.z = f2bf((bf2f(a.z)+bf2f(b.z))*inv);
  o.w = f2bf((bf2f(a.w)+bf2f(b.w))*inv);
  *(ushort4*)(AO+i) = o;
}

extern "C" void kernel_launch(void* const* d_in, const int* in_sizes, int n_in,
                              void* d_out, int out_size, void* d_ws, size_t ws_size,
                              hipStream_t stream)
{
  (void)in_sizes; (void)n_in; (void)out_size; (void)ws_size;
  const float* H     = (const float*)d_in[0];
  // d_in[1] = cu_seqlens (unused by reference)
  const float* cosb  = (const float*)d_in[2];
  const float* sinb  = (const float*)d_in[3];
  const float* Wqkv  = (const float*)d_in[4];
  const float* bqkv  = (const float*)d_in[5];
  const float* Wproj = (const float*)d_in[6];
  const float* bproj = (const float*)d_in[7];
  float* out = (float*)d_out;
  char* ws = (char*)d_ws;
  // 52 MiB layout. Lifetimes: Hb dead after gemm -> Opart0; Qb dead after flash -> AO.
  float* Lpart  = (float*)(ws + 0);         // [2][16][4096] f32, 0.5 MB (1 MB region)
  u16*   WprojT = (u16*)(ws + 2097152);     // 2 MB
  u16*   Hb     = (u16*)(ws + 4194304);     // 8 MB
  u16*   Opart0 = (u16*)(ws + 4194304);     //   (reuses Hb, dead after gemm)
  u16*   Qb     = (u16*)(ws + 12582912);    // 8 MB
  u16*   AO     = (u16*)(ws + 12582912);    //   (reuses Qb, dead after flash)
  u16*   Kb     = (u16*)(ws + 20971520);    // 8 MB
  u16*   VTb    = (u16*)(ws + 29360128);    // 8 MB
  u16*   WqkvT  = (u16*)(ws + 37748736);    // 6 MB
  u16*   Opart1 = (u16*)(ws + 44040192);    // 8 MB (ends 52 MB)

  hipLaunchKernelGGL(prep, dim3(8192), dim3(256), 0, stream, H, Wqkv, Wproj, Hb, WqkvT, WprojT);
  hipLaunchKernelGGL(gemm_qkv_rope, dim3(24,32), dim3(256), 0, stream,
                     Hb, WqkvT, bqkv, cosb, sinb, Qb, Kb, VTb);
  hipLaunchKernelGGL(flash_attn, dim3(1024), dim3(256), 0, stream, Qb, Kb, VTb,
                     Opart0, Opart1, Lpart);
  hipLaunchKernelGGL(combine_softmax2, dim3(4096), dim3(256), 0, stream,
                     Opart0, Opart1, Lpart, AO);
  hipLaunchKernelGGL((gemm_bt_bias<64,float>), dim3(16,32), dim3(256), 0, stream,
                     AO, WprojT, bproj, out, 4096, 1024, 1024);
}